// Round 1
// baseline (425.765 us; speedup 1.0000x reference)
//
#include <hip/hip_runtime.h>
#include <stdint.h>

// GIN inference: 5 layers of (neighbor-sum + (1+eps)h) -> GEMM1+ReLU -> GEMM2[+BN+ReLU]
// All activations bf16, accumulation fp32, MFMA 16x16x32 bf16.

#define NN    20000
#define NE    320000
#define MPAD  20096      // 314 * 64
#define DD    256
#define DOUT  128
#define CAP   64         // max degree capacity (Poisson(16): P(>64) ~ 0)
#define LDST  40         // padded LDS row stride (elems), 16B aligned rows

typedef unsigned short u16;
typedef __attribute__((ext_vector_type(8))) __bf16 bf16x8;
typedef __attribute__((ext_vector_type(4))) float  f32x4;

__device__ __forceinline__ u16 f2b(float f){
  union { float f; uint32_t u; } x; x.f = f;
  uint32_t r = x.u + 0x7FFFu + ((x.u >> 16) & 1u);   // RNE
  return (u16)(r >> 16);
}
__device__ __forceinline__ float blo(uint32_t p){ union{uint32_t u;float f;}x; x.u=p<<16;          return x.f; }
__device__ __forceinline__ float bhi(uint32_t p){ union{uint32_t u;float f;}x; x.u=p&0xFFFF0000u;  return x.f; }

// ---- weight prep: f32 [K][N] -> bf16 [N][K] (transposed, k-contiguous) ----
__global__ __launch_bounds__(256) void prep_weights(
    const float* __restrict__ W1, const float* __restrict__ W2a,
    const float* __restrict__ W2l,
    u16* __restrict__ W1t, u16* __restrict__ W2at, u16* __restrict__ W2lt)
{
  int b = blockIdx.x, k = threadIdx.x;
  if (b < 5*256){
    int layer = b >> 8, n = b & 255;
    W1t[layer*65536 + n*256 + k] = f2b(W1[layer*65536 + k*256 + n]);
  } else if (b < 9*256){
    int bb = b - 5*256; int layer = bb >> 8, n = bb & 255;
    W2at[layer*65536 + n*256 + k] = f2b(W2a[layer*65536 + k*256 + n]);
  } else {
    int n = b - 9*256;                       // 0..127
    W2lt[n*256 + k] = f2b(W2l[k*128 + n]);
  }
}

// ---- CSR build (fixed capacity) ----
__global__ __launch_bounds__(256) void fill_csr(
    const int* __restrict__ src, const int* __restrict__ dst,
    int* __restrict__ cnt, int* __restrict__ csr)
{
  int e = blockIdx.x*256 + threadIdx.x;
  if (e < NE){
    int d = dst[e];
    int slot = atomicAdd(&cnt[d], 1);
    if (slot < CAP) csr[d*CAP + slot] = src[e];
  }
}

// ---- x (f32) -> h (bf16), zero pad rows ----
__global__ __launch_bounds__(256) void x_to_h(const float* __restrict__ x, u16* __restrict__ h)
{
  int row  = blockIdx.x*4 + (threadIdx.x >> 6);
  int lane = threadIdx.x & 63;
  uint2 o;
  if (row < NN){
    float4 f = *(const float4*)(x + (size_t)row*DD + lane*4);
    o.x = (uint32_t)f2b(f.x) | ((uint32_t)f2b(f.y) << 16);
    o.y = (uint32_t)f2b(f.z) | ((uint32_t)f2b(f.w) << 16);
  } else { o.x = 0u; o.y = 0u; }
  *(uint2*)(h + (size_t)row*DD + lane*4) = o;
}

// ---- combine: z[v] = (1+eps)*h[v] + sum_{u->v} h[u]   (one wave per node) ----
__global__ __launch_bounds__(256) void combine(
    const u16* __restrict__ h, const int* __restrict__ cnt,
    const int* __restrict__ csr, const float* __restrict__ eps_arr, int layer,
    u16* __restrict__ z)
{
  int v    = blockIdx.x*4 + (threadIdx.x >> 6);
  int lane = threadIdx.x & 63;
  if (v >= NN){
    *(uint2*)(z + (size_t)v*DD + lane*4) = make_uint2(0u,0u);
    return;
  }
  float e = 1.0f + eps_arr[layer];
  uint2 own = *(const uint2*)(h + (size_t)v*DD + lane*4);
  float s0 = blo(own.x)*e, s1 = bhi(own.x)*e, s2 = blo(own.y)*e, s3 = bhi(own.y)*e;
  int deg = cnt[v]; deg = deg > CAP ? CAP : deg;
  const int* lst = csr + (size_t)v*CAP;
  for (int i = 0; i < deg; ++i){
    int u = __builtin_amdgcn_readfirstlane(lst[i]);   // wave-uniform
    uint2 r = *(const uint2*)(h + (size_t)u*DD + lane*4);
    s0 += blo(r.x); s1 += bhi(r.x); s2 += blo(r.y); s3 += bhi(r.y);
  }
  uint2 o;
  o.x = (uint32_t)f2b(s0) | ((uint32_t)f2b(s1) << 16);
  o.y = (uint32_t)f2b(s2) | ((uint32_t)f2b(s3) << 16);
  *(uint2*)(z + (size_t)v*DD + lane*4) = o;
}

// ---- GEMM: C[M x Ncols] = A[M x 256] @ Bt[Ncols x 256]^T, fused epilogues ----
// mode 0: out_bf = relu(acc + bias)
// mode 1: out_bf = relu((acc + bias - mean)*rsqrt(var+eps)*gamma + beta)
// mode 2: out_f32[row<NN] = acc + bias   (Ncols=128)
__global__ __launch_bounds__(256) void gemm(
    const u16* __restrict__ A, const u16* __restrict__ Bt,
    const float* __restrict__ bias,
    const float* __restrict__ gma, const float* __restrict__ bta,
    const float* __restrict__ mu,  const float* __restrict__ var,
    u16* __restrict__ outb, float* __restrict__ outf, int mode)
{
  __shared__ __align__(16) u16 As[64*LDST];
  __shared__ __align__(16) u16 Bs[128*LDST];
  int tid  = threadIdx.x;
  int lane = tid & 63, wave = tid >> 6;
  int m0 = blockIdx.x * 64;
  int n0 = blockIdx.y * 128;

  f32x4 acc[2][4];
  #pragma unroll
  for (int i=0;i<2;++i)
    #pragma unroll
    for (int j=0;j<4;++j){ f32x4 zr = {0.f,0.f,0.f,0.f}; acc[i][j] = zr; }

  int ra  = tid >> 2;  int ka = (tid & 3) * 8;   // A: 64 rows x 4 chunks
  int rb0 = tid >> 2;  int rb1 = rb0 + 64;       // B: 128 rows x 4 chunks
  const u16* Ag  = A  + (size_t)(m0 + ra ) * DD + ka;
  const u16* Bg0 = Bt + (size_t)(n0 + rb0) * DD + ka;
  const u16* Bg1 = Bt + (size_t)(n0 + rb1) * DD + ka;

  int wr = (wave >> 1) * 32, wc = (wave & 1) * 64;
  const u16* Afr = As + (wr + (lane & 15)) * LDST + (lane >> 4) * 8;
  const u16* Bfr = Bs + (wc + (lane & 15)) * LDST + (lane >> 4) * 8;

  bf16x8 va  = *(const bf16x8*)(Ag);
  bf16x8 vb0 = *(const bf16x8*)(Bg0);
  bf16x8 vb1 = *(const bf16x8*)(Bg1);

  for (int k0 = 0; k0 < DD; k0 += 32){
    __syncthreads();
    *(bf16x8*)(As + ra *LDST + ka) = va;
    *(bf16x8*)(Bs + rb0*LDST + ka) = vb0;
    *(bf16x8*)(Bs + rb1*LDST + ka) = vb1;
    __syncthreads();
    if (k0 + 32 < DD){                         // prefetch next K-slice
      va  = *(const bf16x8*)(Ag  + k0 + 32);
      vb0 = *(const bf16x8*)(Bg0 + k0 + 32);
      vb1 = *(const bf16x8*)(Bg1 + k0 + 32);
    }
    bf16x8 af[2], bfr[4];
    #pragma unroll
    for (int i=0;i<2;++i) af[i]  = *(const bf16x8*)(Afr + i*16*LDST);
    #pragma unroll
    for (int j=0;j<4;++j) bfr[j] = *(const bf16x8*)(Bfr + j*16*LDST);
    #pragma unroll
    for (int i=0;i<2;++i)
      #pragma unroll
      for (int j=0;j<4;++j)
        acc[i][j] = __builtin_amdgcn_mfma_f32_16x16x32_bf16(af[i], bfr[j], acc[i][j], 0,0,0);
  }

  int rbase = (lane >> 4) * 4, cbase = lane & 15;
  #pragma unroll
  for (int j=0;j<4;++j){
    int col = n0 + wc + j*16 + cbase;
    float sc, sh;
    if (mode == 1){
      float s = rsqrtf(var[col] + 1e-5f) * gma[col];
      sc = s;
      sh = (bias[col] - mu[col]) * s + bta[col];
    } else { sc = 1.0f; sh = bias[col]; }
    #pragma unroll
    for (int i=0;i<2;++i){
      #pragma unroll
      for (int r=0;r<4;++r){
        int row = m0 + wr + i*16 + rbase + r;
        float vv = acc[i][j][r] * sc + sh;
        if (mode == 2){
          if (row < NN) outf[(size_t)row * DOUT + col] = vv;
        } else {
          vv = vv > 0.f ? vv : 0.f;
          outb[(size_t)row * DD + col] = f2b(vv);
        }
      }
    }
  }
}

extern "C" void kernel_launch(void* const* d_in, const int* in_sizes, int n_in,
                              void* d_out, int out_size, void* d_ws, size_t ws_size,
                              hipStream_t stream)
{
  const float* x     = (const float*)d_in[0];
  const int*   ei    = (const int*)  d_in[1];
  const float* W1    = (const float*)d_in[2];
  const float* b1    = (const float*)d_in[3];
  const float* W2a   = (const float*)d_in[4];
  const float* b2a   = (const float*)d_in[5];
  const float* W2l   = (const float*)d_in[6];
  const float* b2l   = (const float*)d_in[7];
  const float* eps   = (const float*)d_in[8];
  const float* gma   = (const float*)d_in[9];
  const float* bta   = (const float*)d_in[10];
  const float* mu    = (const float*)d_in[11];
  const float* var   = (const float*)d_in[12];
  float* out = (float*)d_out;

  char* ws = (char*)d_ws;
  size_t off = 0;
  auto alloc = [&](size_t bytes)->void*{
    void* p = ws + off; off += (bytes + 255) & ~(size_t)255; return p;
  };
  u16* h    = (u16*)alloc((size_t)MPAD*DD*2);
  u16* z    = (u16*)alloc((size_t)MPAD*DD*2);
  u16* t    = (u16*)alloc((size_t)MPAD*DD*2);
  int* cnt  = (int*)alloc((size_t)NN*4);
  int* csr  = (int*)alloc((size_t)NN*CAP*4);
  u16* W1t  = (u16*)alloc((size_t)5*65536*2);
  u16* W2at = (u16*)alloc((size_t)4*65536*2);
  u16* W2lt = (u16*)alloc((size_t)32768*2);

  const int* srcA = ei;
  const int* dstA = ei + NE;

  hipMemsetAsync(cnt, 0, (size_t)NN*4, stream);
  prep_weights<<<9*256 + 128, 256, 0, stream>>>(W1, W2a, W2l, W1t, W2at, W2lt);
  fill_csr<<<(NE + 255)/256, 256, 0, stream>>>(srcA, dstA, cnt, csr);
  x_to_h<<<MPAD/4, 256, 0, stream>>>(x, h);

  for (int L = 0; L < 5; ++L){
    combine<<<MPAD/4, 256, 0, stream>>>(h, cnt, csr, eps, L, z);
    dim3 g1(MPAD/64, 2);
    gemm<<<g1, 256, 0, stream>>>(z, W1t + (size_t)L*65536, b1 + L*256,
                                 nullptr, nullptr, nullptr, nullptr,
                                 t, nullptr, 0);
    if (L < 4){
      gemm<<<g1, 256, 0, stream>>>(t, W2at + (size_t)L*65536, b2a + L*256,
                                   gma + L*256, bta + L*256, mu + L*256, var + L*256,
                                   h, nullptr, 1);
    } else {
      dim3 g2(MPAD/64, 1);
      gemm<<<g2, 256, 0, stream>>>(t, W2lt, b2l,
                                   nullptr, nullptr, nullptr, nullptr,
                                   nullptr, out, 2);
    }
  }
}